// Round 7
// baseline (217.072 us; speedup 1.0000x reference)
//
#include <hip/hip_runtime.h>
#include <hip/hip_fp16.h>

typedef unsigned long long u64;
typedef unsigned int u32;
typedef float float4a __attribute__((ext_vector_type(4), aligned(4)));

// Problem constants (setup_inputs: B=8, Hs=Ws=256, H=W=512, niter=5)
#define B_    8
#define HS_   256
#define WS_   256
#define H_    512
#define W_    512
#define HW_   (H_ * W_)
#define TO_Y  16                 // output rows per block
#define WR    36                 // mask window rows = TO_Y + 2*10
#define WCOLS 276                // mask window cols = 256 + 2*10
#define VR    26                 // value plane rows = TO_Y + 2*5
#define VCOLS 266                // value plane cols = 256 + 2*5
#define VSTR  267                // value plane stride (odd)
#define OW    9                  // occ bitmask words per row (276 bits)
#define NBAND 32                 // 16-row bands per batch
#define NBKT  64                 // buckets per batch = band*2 + xhalf
#define INFW  0xFFFFFFFFu
#define CAPB  8192               // bucket capacity (expected ~4.2K, ~2x margin)

// ---------------------------------------------------------------------------
// Bilinear upsample of (src - base), bit-exact vs the numpy reference.
// ---------------------------------------------------------------------------
__device__ __forceinline__ void bilin_disp(const float* __restrict__ src,
                                           const float* __restrict__ base,
                                           int b, int y, int x,
                                           float& dx, float& dy) {
#pragma clang fp contract(off)
    float cy = ((float)y + 0.5f) * 0.5f - 0.5f;
    cy = fminf(fmaxf(cy, 0.0f), 255.0f);
    int   y0 = (int)floorf(cy);
    int   y1 = min(y0 + 1, HS_ - 1);
    float wy = cy - (float)y0;

    float cx = ((float)x + 0.5f) * 0.5f - 0.5f;
    cx = fminf(fmaxf(cx, 0.0f), 255.0f);
    int   x0 = (int)floorf(cx);
    float wx = cx - (float)x0;

    float omy = 1.0f - wy;
    float wA, wB;
    int xs;
    if (x0 >= WS_ - 1) { xs = WS_ - 2; wA = 0.0f; wB = 1.0f; }
    else               { xs = x0;      wA = 1.0f - wx; wB = wx; }

    const float4a* S0 = (const float4a*)(src  + ((b * HS_ + y0) * WS_ + xs) * 2);
    const float4a* S1 = (const float4a*)(src  + ((b * HS_ + y1) * WS_ + xs) * 2);
    const float4a* B0 = (const float4a*)(base + (y0 * WS_ + xs) * 2);
    const float4a* B1 = (const float4a*)(base + (y1 * WS_ + xs) * 2);
    float4a s0 = *S0, s1 = *S1, b0 = *B0, b1 = *B1;

    float a00x = s0.x - b0.x, a00y = s0.y - b0.y;
    float a01x = s0.z - b0.z, a01y = s0.w - b0.w;
    float a10x = s1.x - b1.x, a10y = s1.y - b1.y;
    float a11x = s1.z - b1.z, a11y = s1.w - b1.w;

    float r0x = a00x * omy + a10x * wy;   // blend along y first (matches ref)
    float r0y = a00y * omy + a10y * wy;
    float r1x = a01x * omy + a11x * wy;
    float r1y = a01y * omy + a11y * wy;
    dx = (r0x * wA + r1x * wB) * 256.0f;  // * (W/2), exact pow2
    dy = (r0y * wA + r1y * wB) * 256.0f;
}

__device__ __forceinline__ u32 pack16(float x, float y) {
    __half hx = __float2half_rn(x), hy = __float2half_rn(y);
    return ((u32)__half_as_ushort(hy) << 16) | (u32)__half_as_ushort(hx);
}
__device__ __forceinline__ float2 unpack16(u32 p) {
    float2 f;
    f.x = __half2float(__ushort_as_half((unsigned short)(p & 0xFFFFu)));
    f.y = __half2float(__ushort_as_half((unsigned short)(p >> 16)));
    return f;
}

__device__ __forceinline__ u64 shfl_left(u64 v) {
    unsigned lo = __shfl_up((unsigned)v, 1);
    unsigned hi = __shfl_up((unsigned)(v >> 32), 1);
    u64 r = ((u64)hi << 32) | lo;
    return (threadIdx.x & 63) ? r : 0ull;
}
__device__ __forceinline__ u64 shfl_right(u64 v) {
    unsigned lo = __shfl_down((unsigned)v, 1);
    unsigned hi = __shfl_down((unsigned)(v >> 32), 1);
    u64 r = ((u64)hi << 32) | lo;
    return ((threadIdx.x & 63) == 63) ? 0ull : r;
}

// ---------------------------------------------------------------------------
// Pass 1: EXACT R0 pre_k (verified; ~7us by the R5 overhead decomposition).
// ---------------------------------------------------------------------------
__launch_bounds__(1024)
__global__ void pre_k(const float* __restrict__ src,
                      const float* __restrict__ base,
                      u32* __restrict__ pay,
                      u32* __restrict__ gcount,
                      u32* __restrict__ bucket) {
    __shared__ u32 cnt[NBKT];
    __shared__ u32 bbase[NBKT];

    int bid = blockIdx.x;
    int b   = bid & 7;
    int t   = bid >> 3;                    // 0..255
    int j   = t * 1024 + threadIdx.x;      // per-batch source index
    int y   = j >> 9;
    int x   = j & (W_ - 1);

    if (threadIdx.x < NBKT) cnt[threadIdx.x] = 0;
    __syncthreads();

    float dx, dy;
    bilin_disp(src, base, b, y, x, dx, dy);
    pay[b * HW_ + j] = pack16(-dx, -dy);

    int xi = (int)rintf((float)x + dx);    // round-half-even == jnp.round
    int yi = (int)rintf((float)y + dy);
    bool inb = (xi >= 0 && xi < W_ && yi >= 0 && yi < H_);
    int bk0 = 0, bk1 = -1;
    u32 r0 = 0, r1 = 0, e = 0;
    if (inb) {
        int band = yi >> 4;
        bk0 = band * 2 + (xi >> 8);
        r0 = atomicAdd(&cnt[bk0], 1u);
        if      (xi >= 246 && xi <= 255) bk1 = band * 2 + 1;  // left sliver -> right bucket
        else if (xi >= 256 && xi <= 265) bk1 = band * 2;      // right sliver -> left bucket
        if (bk1 >= 0) r1 = atomicAdd(&cnt[bk1], 1u);
        e = ((u32)(yi & 15) << 27) | ((u32)xi << 18) | (u32)j;
    }
    __syncthreads();
    if (threadIdx.x < NBKT) {
        u32 c = cnt[threadIdx.x];
        bbase[threadIdx.x] = c ? atomicAdd(&gcount[b * NBKT + threadIdx.x], c)
                               : 0u;
    }
    __syncthreads();
    if (inb) {
        u32 s0 = bbase[bk0] + r0;
        if (s0 < CAPB) bucket[(b * NBKT + bk0) * CAPB + s0] = e;
        if (bk1 >= 0) {
            u32 s1 = bbase[bk1] + r1;
            if (s1 < CAPB) bucket[(b * NBKT + bk1) * CAPB + s1] = e;
        }
    }
}

// ---------------------------------------------------------------------------
// Pass 2: EXACT R6 fused5_k (mask/value split; 59.5us measured). Writes out.
// ---------------------------------------------------------------------------
__launch_bounds__(512, 2)
__global__ void fused5_k(const u32* __restrict__ pay,
                         const u32* __restrict__ gcount,
                         const u32* __restrict__ bucket,
                         const float* __restrict__ kern,
                         const float* __restrict__ tgt,
                         float* __restrict__ out) {
    __shared__ u32 plane[VR * VSTR + WR * OW];   // 29064 B
    u32* occ = plane + VR * VSTR;

    int id   = blockIdx.x;                 // 0..511
    int b    = id & 7;                     // batch == XCD (round-robin pin)
    int rest = id >> 3;                    // 0..63
    int tile = rest >> 1;                  // 0..31
    int half = rest & 1;
    int X0   = half << 8;
    int Y0   = tile * TO_Y;
    int w0   = Y0 - 10;                    // mask window row 0 (output coords)
    int wc0  = X0 - 10;                    // mask window col 0 (output coords)
    int tid  = threadIdx.x;

    float kw[9];
#pragma unroll
    for (int q = 0; q < 9; q++) kw[q] = kern[q];

    // ---- phase 0: init value-plane keys + occ bitmask ----
    for (int i = tid; i < VR * VSTR; i += 512) plane[i] = INFW;
    for (int i = tid; i < WR * OW; i += 512) occ[i] = 0u;
    __syncthreads();

    // ---- phase 1: scatter from this half's 2-3 band buckets ----
    {
        int qlo = max(0, w0 >> 4);
        int qhi = min(NBAND - 1, (w0 + WR - 1) >> 4);
        for (int q = qlo; q <= qhi; q++) {
            int bki = b * NBKT + q * 2 + half;
            u32 cntq = min(gcount[bki], (u32)CAPB);
            const u32* bk = bucket + bki * CAPB;
            int ybase = q * 16 - w0;       // band row 0 in window coords
            for (u32 i = tid; i < cntq; i += 512) {
                u32 e  = bk[i];
                int wr = ybase + (int)((e >> 27) & 15u);
                if ((unsigned)wr < WR) {
                    int xc = (int)((e >> 18) & 511u) - wc0;  // always in [0,275]
                    atomicOr(&occ[wr * OW + (xc >> 5)], 1u << (xc & 31));
                    unsigned vr = (unsigned)(wr - 5);
                    unsigned vc = (unsigned)(xc - 5);
                    if (vr < (unsigned)VR && vc < (unsigned)VCOLS)
                        atomicMin(&plane[vr * VSTR + vc], e & 0x3FFFFu);
                }
            }
        }
    }
    __syncthreads();

    // ---- phase 2: per-lane column mask from occ bits ----
    int wv   = tid >> 6;
    int lane = tid & 63;
    int col  = X0 + 32 * wv - 16 + lane;   // output-coord column of this lane
    int cls  = col - wc0;                  // mask window column index
    int clsv = cls - 5;                    // value plane column index
    bool colin = ((unsigned)cls < WCOLS)
                 && (col >= -6) && (col <= W_ + 5);  // padded [-6,517]

    u64 m = 0;
    if (colin) {
        int wsh = cls & 31, wix = cls >> 5;
#pragma unroll 6
        for (int r = 0; r < WR; r++)
            m |= (u64)((occ[r * OW + wix] >> wsh) & 1u) << r;
    }

    // ---- phase 3: in-place key -> payload overwrite (empty -> 0) ----
    {
        const u32* pb = pay + b * HW_;
        for (int idx = tid; idx < VR * VCOLS; idx += 512) {
            int rr = idx / VCOLS;
            int cc = idx - rr * VCOLS;
            int off = rr * VSTR + cc;
            u32 k = plane[off];
            plane[off] = (k != INFW) ? pb[k] : 0u;
        }
    }
    __syncthreads();

    int rlo = max(0, -6 - w0);
    int rhi = min(WR - 1, (W_ + 5) - w0);
    u64 validm = colin ? ((((u64)1 << (rhi - rlo + 1)) - 1) << rlo) : 0ull;

    const u64 VROWS = (((u64)1 << 24) - 1) << 6;   // bits 6..29 (output+-4)
    bool vupd = (lane >= 6 && lane <= 57)
                && (col >= X0 - 4) && (col <= X0 + 259);  // cols output+-4

    // ---- phase 4: 5 diffusion iterations ----
    for (int it = 0; it < 5; it++) {
        u64 mL = shfl_left(m), mR = shfl_right(m);
        u64 cand = ~m & ((m << 1) | (m >> 1) | mL | mR) & validm;
        u64 cv = vupd ? (cand & VROWS) : 0ull;
        while (cv) {
            int r = __builtin_ctzll(cv);   // bits 6..29 -> rv = r-5 in 1..24
            cv &= cv - 1;
            int rv = r - 5;
            float s = 0.0f, ax = 0.0f, ay = 0.0f;
#pragma unroll
            for (int dr = -1; dr <= 1; dr++) {
#pragma unroll
                for (int dc = -1; dc <= 1; dc++) {
                    if (dr == 0 && dc == 0) continue;
                    u64 nm = (dc < 0) ? mL : ((dc > 0) ? mR : m);
                    float wq = ((nm >> (r + dr)) & 1)
                                 ? kw[(dr + 1) * 3 + (dc + 1)] : 0.0f;
                    int cc = min(max(clsv + dc, 0), VCOLS - 1); // clamp: wq==0
                    float2 nv = unpack16(plane[(rv + dr) * VSTR + cc]);
                    s += wq; ax += wq * nv.x; ay += wq * nv.y;
                }
            }
            float rs = __builtin_amdgcn_rcpf(s);   // ~1e-7 rel err, in tol
            plane[rv * VSTR + clsv] = pack16(ax * rs, ay * rs);
        }
        m |= cand;
        __syncthreads();
    }

    // ---- phase 5: 5 erosion iterations (registers only) + compose ----
    for (int it = 0; it < 5; it++) {
        u64 mL = shfl_left(m), mR = shfl_right(m);
        m &= (m << 1) & (m >> 1) & mL & mR;
    }

    if (lane >= 16 && lane < 48) {
#pragma unroll 4
        for (int r = 10; r < 10 + TO_Y; r++) {
            int row = w0 + r;              // Y0 .. Y0+15, always in [0,512)
            bool on = (m >> r) & 1;
            float vx, vy;
            if (on) {
                float2 t = unpack16(plane[(r - 5) * VSTR + clsv]);
                vx = t.x * (1.0f / 256.0f);   // 2/W exact
                vy = t.y * (1.0f / 256.0f);   // 2/H exact
            } else {
                vx = 4.0f; vy = 4.0f;
            }
            int ti = (row * W_ + col) * 2;
            float2 tg = *(const float2*)(tgt + ti);
            float2 ov; ov.x = tg.x + vx; ov.y = tg.y + vy;
            ((float2*)out)[(size_t)b * HW_ + row * W_ + col] = ov;
        }
    }
}

// ---------------------------------------------------------------------------
// ABLATION PROBES (measurement round — R6 post-mortem). Identical body to
// fused5_k, truncated after phase PH:
//   PH=0: init only            -> probe fixed cost (launch+init+checksum)
//   PH=1: +bucket scatter      -> P1-P0 = scatter
//   PH=2: +mask +key->value    -> P2-P1 = mask build + pay gather
//   PH=3: +5x diffusion        -> P3-P2 = diffusion
// fused5_k - P3 ~= erosion + compose. Each probe writes a per-thread
// checksum (keeps plane/occ/m observably live; global store cannot be
// DCE'd) into the pay batch-0 slice. Benign by construction: fused5_k has
// already written `out` before probes run (stream order); pre_k fully
// rewrites pay on every launch; probes never touch gcount/bucket/out.
// Cross-block probe races on pay only corrupt checksum VALUES, which are
// never checked. Probes run at fused5_k's exact geometry/occupancy.
// ---------------------------------------------------------------------------
template<int PH>
__launch_bounds__(512, 2)
__global__ void probe_k(u32* pay,
                        const u32* __restrict__ gcount,
                        const u32* __restrict__ bucket,
                        const float* __restrict__ kern) {
    __shared__ u32 plane[VR * VSTR + WR * OW];
    u32* occ = plane + VR * VSTR;

    int id   = blockIdx.x;
    int b    = id & 7;
    int rest = id >> 3;
    int tile = rest >> 1;
    int half = rest & 1;
    int X0   = half << 8;
    int Y0   = tile * TO_Y;
    int w0   = Y0 - 10;
    int wc0  = X0 - 10;
    int tid  = threadIdx.x;

    // phase 0: init
    for (int i = tid; i < VR * VSTR; i += 512) plane[i] = INFW;
    for (int i = tid; i < WR * OW; i += 512) occ[i] = 0u;
    __syncthreads();

    if constexpr (PH >= 1) {
        int qlo = max(0, w0 >> 4);
        int qhi = min(NBAND - 1, (w0 + WR - 1) >> 4);
        for (int q = qlo; q <= qhi; q++) {
            int bki = b * NBKT + q * 2 + half;
            u32 cntq = min(gcount[bki], (u32)CAPB);
            const u32* bk = bucket + bki * CAPB;
            int ybase = q * 16 - w0;
            for (u32 i = tid; i < cntq; i += 512) {
                u32 e  = bk[i];
                int wr = ybase + (int)((e >> 27) & 15u);
                if ((unsigned)wr < WR) {
                    int xc = (int)((e >> 18) & 511u) - wc0;
                    atomicOr(&occ[wr * OW + (xc >> 5)], 1u << (xc & 31));
                    unsigned vr = (unsigned)(wr - 5);
                    unsigned vc = (unsigned)(xc - 5);
                    if (vr < (unsigned)VR && vc < (unsigned)VCOLS)
                        atomicMin(&plane[vr * VSTR + vc], e & 0x3FFFFu);
                }
            }
        }
    }
    __syncthreads();

    int wv   = tid >> 6;
    int lane = tid & 63;
    int col  = X0 + 32 * wv - 16 + lane;
    int cls  = col - wc0;
    int clsv = cls - 5;
    bool colin = ((unsigned)cls < WCOLS)
                 && (col >= -6) && (col <= W_ + 5);

    u64 m = 0;
    if constexpr (PH >= 2) {
        if (colin) {
            int wsh = cls & 31, wix = cls >> 5;
#pragma unroll 6
            for (int r = 0; r < WR; r++)
                m |= (u64)((occ[r * OW + wix] >> wsh) & 1u) << r;
        }
        {
            const u32* pb = pay + b * HW_;
            for (int idx = tid; idx < VR * VCOLS; idx += 512) {
                int rr = idx / VCOLS;
                int cc = idx - rr * VCOLS;
                int off = rr * VSTR + cc;
                u32 k = plane[off];
                plane[off] = (k != INFW) ? pb[k] : 0u;
            }
        }
    }
    __syncthreads();

    if constexpr (PH >= 3) {
        float kw[9];
#pragma unroll
        for (int q = 0; q < 9; q++) kw[q] = kern[q];

        int rlo = max(0, -6 - w0);
        int rhi = min(WR - 1, (W_ + 5) - w0);
        u64 validm = colin ? ((((u64)1 << (rhi - rlo + 1)) - 1) << rlo) : 0ull;

        const u64 VROWS = (((u64)1 << 24) - 1) << 6;
        bool vupd = (lane >= 6 && lane <= 57)
                    && (col >= X0 - 4) && (col <= X0 + 259);

        for (int it = 0; it < 5; it++) {
            u64 mL = shfl_left(m), mR = shfl_right(m);
            u64 cand = ~m & ((m << 1) | (m >> 1) | mL | mR) & validm;
            u64 cv = vupd ? (cand & VROWS) : 0ull;
            while (cv) {
                int r = __builtin_ctzll(cv);
                cv &= cv - 1;
                int rv = r - 5;
                float s = 0.0f, ax = 0.0f, ay = 0.0f;
#pragma unroll
                for (int dr = -1; dr <= 1; dr++) {
#pragma unroll
                    for (int dc = -1; dc <= 1; dc++) {
                        if (dr == 0 && dc == 0) continue;
                        u64 nm = (dc < 0) ? mL : ((dc > 0) ? mR : m);
                        float wq = ((nm >> (r + dr)) & 1)
                                     ? kw[(dr + 1) * 3 + (dc + 1)] : 0.0f;
                        int cc = min(max(clsv + dc, 0), VCOLS - 1);
                        float2 nv = unpack16(plane[(rv + dr) * VSTR + cc]);
                        s += wq; ax += wq * nv.x; ay += wq * nv.y;
                    }
                }
                float rs = __builtin_amdgcn_rcpf(s);
                plane[rv * VSTR + clsv] = pack16(ax * rs, ay * rs);
            }
            m |= cand;
            __syncthreads();
        }
    }

    // checksum sink — keeps everything live; value never checked
    u32 c = (u32)m ^ (u32)(m >> 32) ^ plane[tid] ^ occ[tid % (WR * OW)];
    pay[(size_t)id * 512 + tid] = c;
}

extern "C" void kernel_launch(void* const* d_in, const int* in_sizes, int n_in,
                              void* d_out, int out_size, void* d_ws, size_t ws_size,
                              hipStream_t stream) {
    const float* src  = (const float*)d_in[0];  // (8,256,256,2)
    const float* kern = (const float*)d_in[1];  // (3,3)
    const float* base = (const float*)d_in[2];  // (1,256,256,2)
    const float* tgt  = (const float*)d_in[3];  // (1,512,512,2)
    float* out = (float*)d_out;                 // (8,512,512,2)

    char* ws = (char*)d_ws;
    u32* gcount = (u32*)ws;                                   // 2 KB (pad 4K)
    u32* pay    = (u32*)(ws + 4096);                          // 8 MB
    u32* bucket = (u32*)(ws + 4096 + (size_t)B_ * HW_ * 4);   // 16.8 MB

    hipMemsetAsync(gcount, 0, B_ * NBKT * sizeof(u32), stream);

    pre_k<<<(B_ * HW_) / 1024, 1024, 0, stream>>>(src, base, pay, gcount, bucket);
    fused5_k<<<512, 512, 0, stream>>>(pay, gcount, bucket, kern, tgt, out);

    // measurement probes (timing read from rocprof per-dispatch durations)
    probe_k<0><<<512, 512, 0, stream>>>(pay, gcount, bucket, kern);
    probe_k<1><<<512, 512, 0, stream>>>(pay, gcount, bucket, kern);
    probe_k<2><<<512, 512, 0, stream>>>(pay, gcount, bucket, kern);
    probe_k<3><<<512, 512, 0, stream>>>(pay, gcount, bucket, kern);
}

// Round 8
// 141.479 us; speedup vs baseline: 1.5343x; 1.5343x over previous
//
#include <hip/hip_runtime.h>
#include <hip/hip_fp16.h>

typedef unsigned long long u64;
typedef unsigned int u32;
typedef float float4a __attribute__((ext_vector_type(4), aligned(4)));

// Problem constants (setup_inputs: B=8, Hs=Ws=256, H=W=512, niter=5)
#define B_    8
#define HS_   256
#define WS_   256
#define H_    512
#define W_    512
#define HW_   (H_ * W_)
#define TO_Y  16                 // output rows per block
#define WR    36                 // mask window rows = TO_Y + 2*10
#define WCOLS 276                // mask window cols = 256 + 2*10
#define VR    26                 // value plane rows = TO_Y + 2*5
#define VCOLS 266                // value plane cols = 256 + 2*5
#define VSTR  267                // value plane stride (odd)
#define OW    9                  // occ bitmask words per row (276 bits)
#define NBAND 32                 // 16-row bands per batch
#define NBKT  64                 // buckets per batch = band*2 + xhalf
#define INFW  0xFFFFFFFFu
#define CAPB  8192               // bucket capacity (expected ~4.2K, ~2x margin)

// ---------------------------------------------------------------------------
// Bilinear upsample of (src - base), bit-exact vs the numpy reference.
// ---------------------------------------------------------------------------
__device__ __forceinline__ void bilin_disp(const float* __restrict__ src,
                                           const float* __restrict__ base,
                                           int b, int y, int x,
                                           float& dx, float& dy) {
#pragma clang fp contract(off)
    float cy = ((float)y + 0.5f) * 0.5f - 0.5f;
    cy = fminf(fmaxf(cy, 0.0f), 255.0f);
    int   y0 = (int)floorf(cy);
    int   y1 = min(y0 + 1, HS_ - 1);
    float wy = cy - (float)y0;

    float cx = ((float)x + 0.5f) * 0.5f - 0.5f;
    cx = fminf(fmaxf(cx, 0.0f), 255.0f);
    int   x0 = (int)floorf(cx);
    float wx = cx - (float)x0;

    float omy = 1.0f - wy;
    float wA, wB;
    int xs;
    if (x0 >= WS_ - 1) { xs = WS_ - 2; wA = 0.0f; wB = 1.0f; }
    else               { xs = x0;      wA = 1.0f - wx; wB = wx; }

    const float4a* S0 = (const float4a*)(src  + ((b * HS_ + y0) * WS_ + xs) * 2);
    const float4a* S1 = (const float4a*)(src  + ((b * HS_ + y1) * WS_ + xs) * 2);
    const float4a* B0 = (const float4a*)(base + (y0 * WS_ + xs) * 2);
    const float4a* B1 = (const float4a*)(base + (y1 * WS_ + xs) * 2);
    float4a s0 = *S0, s1 = *S1, b0 = *B0, b1 = *B1;

    float a00x = s0.x - b0.x, a00y = s0.y - b0.y;
    float a01x = s0.z - b0.z, a01y = s0.w - b0.w;
    float a10x = s1.x - b1.x, a10y = s1.y - b1.y;
    float a11x = s1.z - b1.z, a11y = s1.w - b1.w;

    float r0x = a00x * omy + a10x * wy;   // blend along y first (matches ref)
    float r0y = a00y * omy + a10y * wy;
    float r1x = a01x * omy + a11x * wy;
    float r1y = a01y * omy + a11y * wy;
    dx = (r0x * wA + r1x * wB) * 256.0f;  // * (W/2), exact pow2
    dy = (r0y * wA + r1y * wB) * 256.0f;
}

__device__ __forceinline__ u32 pack16(float x, float y) {
    __half hx = __float2half_rn(x), hy = __float2half_rn(y);
    return ((u32)__half_as_ushort(hy) << 16) | (u32)__half_as_ushort(hx);
}
__device__ __forceinline__ float2 unpack16(u32 p) {
    float2 f;
    f.x = __half2float(__ushort_as_half((unsigned short)(p & 0xFFFFu)));
    f.y = __half2float(__ushort_as_half((unsigned short)(p >> 16)));
    return f;
}

__device__ __forceinline__ u64 shfl_left(u64 v) {
    unsigned lo = __shfl_up((unsigned)v, 1);
    unsigned hi = __shfl_up((unsigned)(v >> 32), 1);
    u64 r = ((u64)hi << 32) | lo;
    return (threadIdx.x & 63) ? r : 0ull;
}
__device__ __forceinline__ u64 shfl_right(u64 v) {
    unsigned lo = __shfl_down((unsigned)v, 1);
    unsigned hi = __shfl_down((unsigned)(v >> 32), 1);
    u64 r = ((u64)hi << 32) | lo;
    return ((threadIdx.x & 63) == 63) ? 0ull : r;
}

// ---------------------------------------------------------------------------
// Pass 1: EXACT R0 pre_k (verified; ~7us by the R5 overhead decomposition).
// ---------------------------------------------------------------------------
__launch_bounds__(1024)
__global__ void pre_k(const float* __restrict__ src,
                      const float* __restrict__ base,
                      u32* __restrict__ pay,
                      u32* __restrict__ gcount,
                      u32* __restrict__ bucket) {
    __shared__ u32 cnt[NBKT];
    __shared__ u32 bbase[NBKT];

    int bid = blockIdx.x;
    int b   = bid & 7;
    int t   = bid >> 3;                    // 0..255
    int j   = t * 1024 + threadIdx.x;      // per-batch source index
    int y   = j >> 9;
    int x   = j & (W_ - 1);

    if (threadIdx.x < NBKT) cnt[threadIdx.x] = 0;
    __syncthreads();

    float dx, dy;
    bilin_disp(src, base, b, y, x, dx, dy);
    pay[b * HW_ + j] = pack16(-dx, -dy);

    int xi = (int)rintf((float)x + dx);    // round-half-even == jnp.round
    int yi = (int)rintf((float)y + dy);
    bool inb = (xi >= 0 && xi < W_ && yi >= 0 && yi < H_);
    int bk0 = 0, bk1 = -1;
    u32 r0 = 0, r1 = 0, e = 0;
    if (inb) {
        int band = yi >> 4;
        bk0 = band * 2 + (xi >> 8);
        r0 = atomicAdd(&cnt[bk0], 1u);
        if      (xi >= 246 && xi <= 255) bk1 = band * 2 + 1;  // left sliver -> right bucket
        else if (xi >= 256 && xi <= 265) bk1 = band * 2;      // right sliver -> left bucket
        if (bk1 >= 0) r1 = atomicAdd(&cnt[bk1], 1u);
        e = ((u32)(yi & 15) << 27) | ((u32)xi << 18) | (u32)j;
    }
    __syncthreads();
    if (threadIdx.x < NBKT) {
        u32 c = cnt[threadIdx.x];
        bbase[threadIdx.x] = c ? atomicAdd(&gcount[b * NBKT + threadIdx.x], c)
                               : 0u;
    }
    __syncthreads();
    if (inb) {
        u32 s0 = bbase[bk0] + r0;
        if (s0 < CAPB) bucket[(b * NBKT + bk0) * CAPB + s0] = e;
        if (bk1 >= 0) {
            u32 s1 = bbase[bk1] + r1;
            if (s1 < CAPB) bucket[(b * NBKT + bk1) * CAPB + s1] = e;
        }
    }
}

// ---------------------------------------------------------------------------
// Pass 2: fused stencil. Phases 0-3 EXACT R6 (verified). Phases 4-6
// rewritten REGISTER-RESIDENT per the R7 ablation:
//
// R7 probe arithmetic (sum of 4 cumulative probes + gaps = 77.9us, each
// probe <= fused=59.8): the ONLY consistent decomposition is
// init+scatter+mask+gather ~15us, diffusion ~45us. The old diffusion was
// a divergent while(cv) loop doing 9 scattered LDS ops per filled cell
// (~2.5K fills/block, ~4-way conflicts = the 2.1M conflict cycles) with a
// lgkmcnt(0) chain per fill, serializing 16 waves on the per-CU LDS pipe.
//
// New phase 4: lane = column; each lane holds its 26-row value column in
// registers (u32 v[26], packed half2). Left/right-column taps come from
// __shfl of the neighbor lane's register (conflict-free, no addresses).
// Rows sweep statically unrolled (static v[] indices — no scratch), gated
// by __any(cand bit in wave) so post-frontier iterations are ~free. No
// LDS reads/writes/barriers in diffusion at all.
//
// Correctness: update set (VROWS bits 6..29, cols output+-4, lanes 6..57),
// candidate rule, and all halo/staleness gating are BIT-IDENTICAL to the
// verified R6 kernel; only storage (LDS->reg) and traversal (per-fill ->
// per-row branchless) change. In-place safety is now structural: a tap of
// a cell updated earlier in the same sweep (row r-1, or a shuffled lane's
// same-row value) is always weighted by the OLD mask bit of that cell,
// which is 0 for freshly-filled cells => wq=0 exact. All register values
// stay finite (phase 3 zeroes empties; payloads finite), so wq=0 taps add
// exact 0 (R6 lesson). A lane computing a row it won't store may produce
// s=0 -> Inf/NaN — discarded by the per-lane select. Compose reads
// v[5..20] with static indices.
// ---------------------------------------------------------------------------
__launch_bounds__(512, 2)
__global__ void fused5_k(const u32* __restrict__ pay,
                         const u32* __restrict__ gcount,
                         const u32* __restrict__ bucket,
                         const float* __restrict__ kern,
                         const float* __restrict__ tgt,
                         float* __restrict__ out) {
    __shared__ u32 plane[VR * VSTR + WR * OW];   // 29064 B
    u32* occ = plane + VR * VSTR;

    int id   = blockIdx.x;                 // 0..511
    int b    = id & 7;                     // batch == XCD (round-robin pin)
    int rest = id >> 3;                    // 0..63
    int tile = rest >> 1;                  // 0..31
    int half = rest & 1;
    int X0   = half << 8;
    int Y0   = tile * TO_Y;
    int w0   = Y0 - 10;                    // mask window row 0 (output coords)
    int wc0  = X0 - 10;                    // mask window col 0 (output coords)
    int tid  = threadIdx.x;

    float kw[9];
#pragma unroll
    for (int q = 0; q < 9; q++) kw[q] = kern[q];

    // ---- phase 0: init value-plane keys + occ bitmask ----
    for (int i = tid; i < VR * VSTR; i += 512) plane[i] = INFW;
    for (int i = tid; i < WR * OW; i += 512) occ[i] = 0u;
    __syncthreads();

    // ---- phase 1: scatter from this half's 2-3 band buckets ----
    {
        int qlo = max(0, w0 >> 4);
        int qhi = min(NBAND - 1, (w0 + WR - 1) >> 4);
        for (int q = qlo; q <= qhi; q++) {
            int bki = b * NBKT + q * 2 + half;
            u32 cntq = min(gcount[bki], (u32)CAPB);
            const u32* bk = bucket + bki * CAPB;
            int ybase = q * 16 - w0;       // band row 0 in window coords
            for (u32 i = tid; i < cntq; i += 512) {
                u32 e  = bk[i];
                int wr = ybase + (int)((e >> 27) & 15u);
                if ((unsigned)wr < WR) {
                    int xc = (int)((e >> 18) & 511u) - wc0;  // always in [0,275]
                    atomicOr(&occ[wr * OW + (xc >> 5)], 1u << (xc & 31));
                    unsigned vr = (unsigned)(wr - 5);
                    unsigned vc = (unsigned)(xc - 5);
                    if (vr < (unsigned)VR && vc < (unsigned)VCOLS)
                        atomicMin(&plane[vr * VSTR + vc], e & 0x3FFFFu);
                }
            }
        }
    }
    __syncthreads();

    // ---- phase 2: per-lane column mask from occ bits ----
    int wv   = tid >> 6;
    int lane = tid & 63;
    int col  = X0 + 32 * wv - 16 + lane;   // output-coord column of this lane
    int cls  = col - wc0;                  // mask window column index
    int clsv = cls - 5;                    // value plane column index
    bool colin = ((unsigned)cls < WCOLS)
                 && (col >= -6) && (col <= W_ + 5);  // padded [-6,517]

    u64 m = 0;
    if (colin) {
        int wsh = cls & 31, wix = cls >> 5;
#pragma unroll 6
        for (int r = 0; r < WR; r++)
            m |= (u64)((occ[r * OW + wix] >> wsh) & 1u) << r;
    }

    // ---- phase 3: in-place key -> payload overwrite (empty -> 0) ----
    {
        const u32* pb = pay + b * HW_;
        for (int idx = tid; idx < VR * VCOLS; idx += 512) {
            int rr = idx / VCOLS;
            int cc = idx - rr * VCOLS;
            int off = rr * VSTR + cc;
            u32 k = plane[off];
            plane[off] = (k != INFW) ? pb[k] : 0u;
        }
    }
    __syncthreads();

    // ---- phase 3.5: load this lane's value column into registers ----
    u32 v[VR];
    {
        int ccl = min(max(clsv, 0), VCOLS - 1);   // OOB lanes: finite garbage,
#pragma unroll                                    // always wq=0-masked
        for (int rv = 0; rv < VR; ++rv)
            v[rv] = plane[rv * VSTR + ccl];
    }

    int rlo = max(0, -6 - w0);
    int rhi = min(WR - 1, (W_ + 5) - w0);
    u64 validm = colin ? ((((u64)1 << (rhi - rlo + 1)) - 1) << rlo) : 0ull;

    const u64 VROWS = (((u64)1 << 24) - 1) << 6;   // bits 6..29 (output+-4)
    bool vupd = (lane >= 6 && lane <= 57)
                && (col >= X0 - 4) && (col <= X0 + 259);  // cols output+-4

    // ---- phase 4: 5 diffusion iterations, registers + shuffles only ----
#define TAP(val, on, w)                                         \
    {                                                           \
        float wq = (on) ? (w) : 0.0f;                           \
        float2 f_ = unpack16(val);                              \
        s += wq; ax += wq * f_.x; ay += wq * f_.y;              \
    }
#pragma unroll 1
    for (int it = 0; it < 5; it++) {
        u64 mL = shfl_left(m), mR = shfl_right(m);
        u64 cand = ~m & ((m << 1) | (m >> 1) | mL | mR) & validm;
        u64 cv = vupd ? (cand & VROWS) : 0ull;
#pragma unroll
        for (int r = 6; r <= 29; ++r) {
            if (__any((int)((cv >> r) & 1))) {
                const int rv = r - 5;                 // 1..24, static
                u32 cm = v[rv - 1], cp = v[rv + 1];
                u32 lm = __shfl_up(v[rv - 1], 1);
                u32 l0 = __shfl_up(v[rv],     1);
                u32 lp = __shfl_up(v[rv + 1], 1);
                u32 rm = __shfl_down(v[rv - 1], 1);
                u32 r0 = __shfl_down(v[rv],     1);
                u32 rp = __shfl_down(v[rv + 1], 1);
                float s = 0.0f, ax = 0.0f, ay = 0.0f;
                TAP(cm, (m  >> (r - 1)) & 1, kw[1]);
                TAP(cp, (m  >> (r + 1)) & 1, kw[7]);
                TAP(lm, (mL >> (r - 1)) & 1, kw[0]);
                TAP(l0, (mL >>  r     ) & 1, kw[3]);
                TAP(lp, (mL >> (r + 1)) & 1, kw[6]);
                TAP(rm, (mR >> (r - 1)) & 1, kw[2]);
                TAP(r0, (mR >>  r     ) & 1, kw[5]);
                TAP(rp, (mR >> (r + 1)) & 1, kw[8]);
                float rs = __builtin_amdgcn_rcpf(s);  // ~1e-7 rel err, in tol
                u32 nv = pack16(ax * rs, ay * rs);
                if ((cv >> r) & 1) v[rv] = nv;        // per-lane select
            }
        }
        m |= cand;
    }
#undef TAP

    // ---- phase 5: 5 erosion iterations (registers only) + compose ----
    for (int it = 0; it < 5; it++) {
        u64 mL = shfl_left(m), mR = shfl_right(m);
        m &= (m << 1) & (m >> 1) & mL & mR;
    }

    if (lane >= 16 && lane < 48) {
#pragma unroll
        for (int r = 10; r < 10 + TO_Y; r++) {
            int row = w0 + r;              // Y0 .. Y0+15, always in [0,512)
            bool on = (m >> r) & 1;
            float vx, vy;
            if (on) {
                float2 t = unpack16(v[r - 5]);   // v[5..20], static
                vx = t.x * (1.0f / 256.0f);   // 2/W exact
                vy = t.y * (1.0f / 256.0f);   // 2/H exact
            } else {
                vx = 4.0f; vy = 4.0f;
            }
            int ti = (row * W_ + col) * 2;
            float2 tg = *(const float2*)(tgt + ti);
            float2 ov; ov.x = tg.x + vx; ov.y = tg.y + vy;
            ((float2*)out)[(size_t)b * HW_ + row * W_ + col] = ov;
        }
    }
}

extern "C" void kernel_launch(void* const* d_in, const int* in_sizes, int n_in,
                              void* d_out, int out_size, void* d_ws, size_t ws_size,
                              hipStream_t stream) {
    const float* src  = (const float*)d_in[0];  // (8,256,256,2)
    const float* kern = (const float*)d_in[1];  // (3,3)
    const float* base = (const float*)d_in[2];  // (1,256,256,2)
    const float* tgt  = (const float*)d_in[3];  // (1,512,512,2)
    float* out = (float*)d_out;                 // (8,512,512,2)

    char* ws = (char*)d_ws;
    u32* gcount = (u32*)ws;                                   // 2 KB (pad 4K)
    u32* pay    = (u32*)(ws + 4096);                          // 8 MB
    u32* bucket = (u32*)(ws + 4096 + (size_t)B_ * HW_ * 4);   // 16.8 MB

    hipMemsetAsync(gcount, 0, B_ * NBKT * sizeof(u32), stream);

    pre_k<<<(B_ * HW_) / 1024, 1024, 0, stream>>>(src, base, pay, gcount, bucket);
    fused5_k<<<512, 512, 0, stream>>>(pay, gcount, bucket, kern, tgt, out);
}